// Round 1
// baseline (806.408 us; speedup 1.0000x reference)
//
#include <hip/hip_runtime.h>
#include <math.h>

#define V 8
#define H 128
#define W 128
#define C 512
#define P 128
#define HW (H*W)
#define NPTS (V*HW)          // 131072
#define MAXI ((1<<20)-1)
#define ROWCAP 16384         // hard upper bound on unique voxels (analysis: <= ~5.4k)
#define HSIZE (1<<18)
#define HMASK (HSIZE-1)
#define EMPTYK 0xFFFFFFFFFFFFFFFFull

__device__ __forceinline__ float softplusf(float x){
  return fmaxf(x, 0.0f) + log1pf(expf(-fabsf(x)));
}
__device__ __forceinline__ float geluf(float x){
  return 0.5f * x * (1.0f + erff(x * 0.70710678118654752440f));
}

// ---- per-view inverse matrices: prep[v*21] = Kinv(9), Einv[:3,:4](12) ----
__global__ void k_prep(const float* __restrict__ Kmat, const float* __restrict__ Emat,
                       float* __restrict__ prep){
  int v = threadIdx.x;
  if (v >= V) return;
  const float* K = Kmat + v*9;
  float a=K[0],b=K[1],c=K[2],d=K[3],e=K[4],f=K[5],g=K[6],h=K[7],i=K[8];
  float det = a*(e*i-f*h) - b*(d*i-f*g) + c*(d*h-e*g);
  float inv = 1.0f/det;
  float* o = prep + v*21;
  o[0]=(e*i-f*h)*inv; o[1]=(c*h-b*i)*inv; o[2]=(b*f-c*e)*inv;
  o[3]=(f*g-d*i)*inv; o[4]=(a*i-c*g)*inv; o[5]=(c*d-a*f)*inv;
  o[6]=(d*h-e*g)*inv; o[7]=(b*g-a*h)*inv; o[8]=(a*e-b*d)*inv;
  const float* E = Emat + v*12; // [3][4] world->cam
  float r00=E[0],r01=E[1],r02=E[2],t0=E[3];
  float r10=E[4],r11=E[5],r12=E[6],t1=E[7];
  float r20=E[8],r21=E[9],r22=E[10],t2=E[11];
  float rdet = r00*(r11*r22-r12*r21) - r01*(r10*r22-r12*r20) + r02*(r10*r21-r11*r20);
  float rinv = 1.0f/rdet;
  float i00=(r11*r22-r12*r21)*rinv, i01=(r02*r21-r01*r22)*rinv, i02=(r01*r12-r02*r11)*rinv;
  float i10=(r12*r20-r10*r22)*rinv, i11=(r00*r22-r02*r20)*rinv, i12=(r02*r10-r00*r12)*rinv;
  float i20=(r10*r21-r11*r20)*rinv, i21=(r01*r20-r00*r21)*rinv, i22=(r00*r11-r01*r10)*rinv;
  o[9]=i00;  o[10]=i01; o[11]=i02; o[12]=-(i00*t0+i01*t1+i02*t2);
  o[13]=i10; o[14]=i11; o[15]=i12; o[16]=-(i10*t0+i11*t1+i12*t2);
  o[17]=i20; o[18]=i21; o[19]=i22; o[20]=-(i20*t0+i21*t1+i22*t2);
}

// ---- per point: backproject, voxel id, hash insert, score + per-slot max ----
__global__ __launch_bounds__(256) void k_points(const float* __restrict__ depth,
    const float* __restrict__ conf, const float* __restrict__ prep,
    unsigned long long* __restrict__ hkeys, int* __restrict__ maxbits,
    int* __restrict__ slotp, float* __restrict__ scoreb){
  int p = blockIdx.x*256 + threadIdx.x;
  int v = p >> 14;
  int pix = p & (HW-1);
  float fx = (float)(pix & 127);
  float fy = (float)(pix >> 7);
  const float* pr = prep + v*21;
  float d = depth[p];
  float cx = (pr[0]*fx + pr[1]*fy + pr[2]) * d;
  float cy = (pr[3]*fx + pr[4]*fy + pr[5]) * d;
  float cz = (pr[6]*fx + pr[7]*fy + pr[8]) * d;
  float wx = pr[9]*cx  + pr[10]*cy + pr[11]*cz + pr[12];
  float wy = pr[13]*cx + pr[14]*cy + pr[15]*cz + pr[16];
  float wz = pr[17]*cx + pr[18]*cy + pr[19]*cz + pr[20];
  long long ix = (long long)rintf(wx / 0.05f);
  long long iy = (long long)rintf(wy / 0.05f);
  long long iz = (long long)rintf(wz / 0.05f);
  ix = ix < 0 ? 0 : (ix > MAXI ? (long long)MAXI : ix);
  iy = iy < 0 ? 0 : (iy > MAXI ? (long long)MAXI : iy);
  iz = iz < 0 ? 0 : (iz > MAXI ? (long long)MAXI : iz);
  unsigned long long vid = ((unsigned long long)ix << 40) |
                           ((unsigned long long)iy << 20) |
                            (unsigned long long)iz;
  unsigned int slot = (unsigned int)((vid * 0x9E3779B97F4A7C15ull) >> 46) & HMASK;
  for (;;){
    unsigned long long k = hkeys[slot];
    if (k == vid) break;
    if (k == EMPTYK){
      unsigned long long prev = atomicCAS(&hkeys[slot], EMPTYK, vid);
      if (prev == EMPTYK || prev == vid) break;
      // lost race to a different key: re-examine same slot next iteration
    } else {
      slot = (slot + 1) & HMASK;
    }
  }
  slotp[p] = slot;
  float sc = softplusf(conf[p]);
  scoreb[p] = sc;
  atomicMax(&maxbits[slot], __float_as_int(sc));  // sc > 0 so int ordering is valid
}

// ---- compact occupied slots -> unordered unique list ----
__global__ __launch_bounds__(256) void k_compact(const unsigned long long* __restrict__ hkeys,
    int* __restrict__ slot2u, unsigned long long* __restrict__ ukeys, int* __restrict__ Sc){
  int s = blockIdx.x*256 + threadIdx.x;
  unsigned long long k = hkeys[s];
  if (k != EMPTYK){
    int j = atomicAdd(Sc, 1);
    if (j < ROWCAP){ ukeys[j] = k; slot2u[s] = j; }
  }
}

// ---- rank = count of smaller keys => sorted row id (matches jnp.unique order) ----
__global__ __launch_bounds__(256) void k_rank(const unsigned long long* __restrict__ ukeys,
    int* __restrict__ rowofu, unsigned long long* __restrict__ skeys, const int* __restrict__ Sc){
  __shared__ unsigned long long ch[256];
  int S = *Sc; if (S > ROWCAP) S = ROWCAP;
  int j = blockIdx.x*256 + threadIdx.x;
  unsigned long long key = (j < S) ? ukeys[j] : 0ull;
  int rank = 0;
  for (int base = 0; base < S; base += 256){
    int i = base + threadIdx.x;
    ch[threadIdx.x] = (i < S) ? ukeys[i] : EMPTYK;
    __syncthreads();
    int lim = S - base; if (lim > 256) lim = 256;
    if (j < S){
      for (int t = 0; t < lim; t++) rank += (ch[t] < key) ? 1 : 0;
    }
    __syncthreads();
  }
  if (j < S){ rowofu[j] = rank; skeys[rank] = key; }
}

// ---- per point: row id, exp(score-max), denom accumulation ----
__global__ __launch_bounds__(256) void k_pass2(const int* __restrict__ slotp,
    const float* __restrict__ scoreb, const int* __restrict__ maxbits,
    const int* __restrict__ slot2u, const int* __restrict__ rowofu,
    int* __restrict__ rowb, float* __restrict__ ebuf, float* __restrict__ denom){
  int p = blockIdx.x*256 + threadIdx.x;
  int slot = slotp[p];
  int row = rowofu[slot2u[slot]];
  rowb[p] = row;
  float e = expf(scoreb[p] - __int_as_float(maxbits[slot]));
  ebuf[p] = e;
  atomicAdd(&denom[row], e);
}

// ---- weighted feature scatter into d_out (vfeat), run-length reduced atomics ----
__global__ __launch_bounds__(256) void k_scatter(const float* __restrict__ feats,
    const int* __restrict__ rowb, const float* __restrict__ ebuf,
    const float* __restrict__ denom, float* __restrict__ out){
  __shared__ int rows[64];
  __shared__ float wgt[64];
  int p0 = blockIdx.x * 64;
  int tid = threadIdx.x;
  if (tid < 64){
    int r = rowb[p0 + tid];
    rows[tid] = r;
    wgt[tid] = ebuf[p0 + tid] / fmaxf(denom[r], 1e-12f);
  }
  __syncthreads();
  float acc0 = 0.f, acc1 = 0.f;
  int cur = rows[0];
  const float* fp = feats + (size_t)p0 * C + tid;
  for (int i = 0; i < 64; i++){
    int r = rows[i];
    if (r != cur){
      atomicAdd(&out[(size_t)cur*C + tid], acc0);
      atomicAdd(&out[(size_t)cur*C + tid + 256], acc1);
      acc0 = acc1 = 0.f; cur = r;
    }
    float w = wgt[i];
    acc0 += fp[0]   * w;
    acc1 += fp[256] * w;
    fp += C;
  }
  atomicAdd(&out[(size_t)cur*C + tid], acc0);
  atomicAdd(&out[(size_t)cur*C + tid + 256], acc1);
}

// ---- fp32 GEMM: C[m,n] = A[m,:]@B[:,n] + bias ; A optionally split (K1 | rest) ----
// BM=BN=128, BK=16, 256 threads, 8x8 microtile. Rows >= S skipped.
__global__ __launch_bounds__(256) void k_gemm(const float* __restrict__ A1, int lda1, int K1,
    const float* __restrict__ A2, int lda2,
    const float* __restrict__ B, const float* __restrict__ bias,
    float* __restrict__ Cout, int Kdim, const int* __restrict__ Sc){
  int S = *Sc; if (S > ROWCAP) S = ROWCAP;
  int m0 = blockIdx.y * 128;
  if (m0 >= S) return;
  int n0 = blockIdx.x * 128;
  __shared__ float As[16][132];
  __shared__ float Bs[16][132];
  int tid = threadIdx.x;
  int tx = tid & 15, ty = tid >> 4;
  float acc[8][8];
  #pragma unroll
  for (int i=0;i<8;i++)
    #pragma unroll
    for (int j=0;j<8;j++) acc[i][j]=0.f;
  for (int kb = 0; kb < Kdim; kb += 16){
    #pragma unroll
    for (int it = 0; it < 2; it++){
      int id = tid + it*256;            // 512 float4 loads of A (128 rows x 16 k)
      int m = id >> 2, kq = id & 3;
      int kg = kb + kq*4;
      float4 av = make_float4(0.f,0.f,0.f,0.f);
      int gm = m0 + m;
      if (gm < S){
        const float* src;
        if (kg < K1) src = A1 + (size_t)gm*lda1 + kg;
        else         src = A2 + (size_t)gm*lda2 + (kg - K1);
        av = *(const float4*)src;
      }
      As[kq*4+0][m]=av.x; As[kq*4+1][m]=av.y; As[kq*4+2][m]=av.z; As[kq*4+3][m]=av.w;
    }
    #pragma unroll
    for (int it = 0; it < 2; it++){
      int id = tid + it*256;            // 512 float4 loads of B (16 k x 128 n)
      int n4 = id & 31, k = id >> 5;
      float4 bv = *(const float4*)(B + (size_t)(kb+k)*C + n0 + n4*4);
      *(float4*)&Bs[k][n4*4] = bv;
    }
    __syncthreads();
    #pragma unroll
    for (int kk = 0; kk < 16; kk++){
      float a8[8], b8[8];
      *(float4*)&a8[0] = *(const float4*)&As[kk][ty*8];
      *(float4*)&a8[4] = *(const float4*)&As[kk][ty*8+4];
      *(float4*)&b8[0] = *(const float4*)&Bs[kk][tx*8];
      *(float4*)&b8[4] = *(const float4*)&Bs[kk][tx*8+4];
      #pragma unroll
      for (int i=0;i<8;i++)
        #pragma unroll
        for (int j=0;j<8;j++)
          acc[i][j] = fmaf(a8[i], b8[j], acc[i][j]);
    }
    __syncthreads();
  }
  #pragma unroll
  for (int i=0;i<8;i++){
    int m = m0 + ty*8 + i;
    if (m >= S) continue;
    float* cp = Cout + (size_t)m*C + n0 + tx*8;
    #pragma unroll
    for (int j=0;j<8;j++) cp[j] = acc[i][j] + bias[n0 + tx*8 + j];
  }
}

// ---- LayerNorm + exact GELU over rows of [*,512] ----
__global__ __launch_bounds__(256) void k_ln_gelu(const float* __restrict__ in,
    float* __restrict__ outp, const float* __restrict__ g, const float* __restrict__ b,
    const int* __restrict__ Sc){
  int S = *Sc; if (S > ROWCAP) S = ROWCAP;
  __shared__ float red[8];
  int lane = threadIdx.x & 63, wid = threadIdx.x >> 6;
  for (int row = blockIdx.x; row < S; row += gridDim.x){
    float x0 = in[(size_t)row*C + threadIdx.x];
    float x1 = in[(size_t)row*C + threadIdx.x + 256];
    float s = x0 + x1;
    for (int o_=32;o_;o_>>=1) s += __shfl_down(s, o_);
    if (lane == 0) red[wid] = s;
    __syncthreads();
    float mu = (red[0]+red[1]+red[2]+red[3]) * (1.0f/C);
    __syncthreads();
    float d0 = x0-mu, d1 = x1-mu;
    float q = d0*d0 + d1*d1;
    for (int o_=32;o_;o_>>=1) q += __shfl_down(q, o_);
    if (lane == 0) red[wid] = q;
    __syncthreads();
    float var = (red[0]+red[1]+red[2]+red[3]) * (1.0f/C);
    float rs = rsqrtf(var + 1e-5f);
    float y0 = d0*rs*g[threadIdx.x]     + b[threadIdx.x];
    float y1 = d1*rs*g[threadIdx.x+256] + b[threadIdx.x+256];
    outp[(size_t)row*C + threadIdx.x]       = geluf(y0);
    outp[(size_t)row*C + threadIdx.x + 256] = geluf(y1);
    __syncthreads();
  }
}

// ---- positional MLP: centers(3) -> 128 -> SiLU -> 128 ----
__global__ __launch_bounds__(256) void k_pos(const unsigned long long* __restrict__ skeys,
    const float* __restrict__ wp1, const float* __restrict__ bp1,
    const float* __restrict__ wp2, const float* __restrict__ bp2,
    float* __restrict__ pebuf, const int* __restrict__ Sc){
  int S = *Sc; if (S > ROWCAP) S = ROWCAP;
  int r0 = blockIdx.x * 8;
  if (r0 >= S) return;
  __shared__ float t1[8][128];
  __shared__ float cen[8][4];
  int tid = threadIdx.x;
  if (tid < 8){
    int r = r0 + tid;
    unsigned long long key = (r < S) ? skeys[r] : 0ull;
    cen[tid][0] = (float)(int)((key >> 40) & MAXI) * 0.05f;
    cen[tid][1] = (float)(int)((key >> 20) & MAXI) * 0.05f;
    cen[tid][2] = (float)(int)(key & MAXI) * 0.05f;
  }
  __syncthreads();
  #pragma unroll
  for (int it=0; it<4; it++){
    int idx = tid + it*256;
    int r = idx >> 7, j = idx & 127;
    float a = cen[r][0]*wp1[j] + cen[r][1]*wp1[P + j] + cen[r][2]*wp1[2*P + j] + bp1[j];
    t1[r][j] = a / (1.0f + expf(-a));   // SiLU
  }
  __syncthreads();
  #pragma unroll
  for (int it=0; it<4; it++){
    int idx = tid + it*256;
    int r = idx >> 7, j = idx & 127;
    if (r0 + r < S){
      float acc = bp2[j];
      for (int k=0;k<P;k++) acc = fmaf(t1[r][k], wp2[k*P + j], acc);
      pebuf[(size_t)(r0+r)*P + j] = acc;
    }
  }
}

extern "C" void kernel_launch(void* const* d_in, const int* in_sizes, int n_in,
                              void* d_out, int out_size, void* d_ws, size_t ws_size,
                              hipStream_t stream){
  const float* features = (const float*)d_in[0];
  const float* depth    = (const float*)d_in[1];
  const float* intr     = (const float*)d_in[2];
  const float* extr     = (const float*)d_in[3];
  const float* conf     = (const float*)d_in[4];
  const float* w1  = (const float*)d_in[5];
  const float* b1  = (const float*)d_in[6];
  const float* g1  = (const float*)d_in[7];
  const float* be1 = (const float*)d_in[8];
  const float* w2  = (const float*)d_in[9];
  const float* b2  = (const float*)d_in[10];
  const float* wp1 = (const float*)d_in[11];
  const float* bp1 = (const float*)d_in[12];
  const float* wp2 = (const float*)d_in[13];
  const float* bp2 = (const float*)d_in[14];
  const float* wf  = (const float*)d_in[15];
  const float* bf  = (const float*)d_in[16];
  const float* g2  = (const float*)d_in[17];
  const float* be2 = (const float*)d_in[18];

  char* ws = (char*)d_ws;
  size_t o = 0;
  auto alloc = [&](size_t bytes){ void* p = ws + o; o += (bytes + 255) & ~size_t(255); return p; };
  unsigned long long* hkeys  = (unsigned long long*)alloc((size_t)HSIZE*8);
  int*   slot2u  = (int*)alloc((size_t)HSIZE*4);
  int*   maxbits = (int*)alloc((size_t)HSIZE*4);
  int*   Sc      = (int*)alloc(256);
  float* prep    = (float*)alloc(V*21*4);
  int*   slotp   = (int*)alloc((size_t)NPTS*4);
  float* scoreb  = (float*)alloc((size_t)NPTS*4);
  float* ebuf    = (float*)alloc((size_t)NPTS*4);
  int*   rowb    = (int*)alloc((size_t)NPTS*4);
  unsigned long long* ukeys = (unsigned long long*)alloc((size_t)ROWCAP*8);
  int*   rowofu  = (int*)alloc((size_t)ROWCAP*4);
  unsigned long long* skeys = (unsigned long long*)alloc((size_t)ROWCAP*8);
  float* denom   = (float*)alloc((size_t)ROWCAP*4);
  float* hbufA   = (float*)alloc((size_t)ROWCAP*C*4);
  float* hbufB   = (float*)alloc((size_t)ROWCAP*C*4);
  float* pebuf   = (float*)alloc((size_t)ROWCAP*P*4);
  // total ~83 MB of d_ws

  float* outp = (float*)d_out;

  hipMemsetAsync(hkeys, 0xFF, (size_t)HSIZE*8, stream);
  hipMemsetAsync(maxbits, 0, (size_t)HSIZE*4, stream);
  hipMemsetAsync(Sc, 0, 4, stream);
  hipMemsetAsync(denom, 0, (size_t)ROWCAP*4, stream);
  hipMemsetAsync(d_out, 0, (size_t)out_size*4, stream);

  k_prep<<<1, 64, 0, stream>>>(intr, extr, prep);
  k_points<<<NPTS/256, 256, 0, stream>>>(depth, conf, prep, hkeys, maxbits, slotp, scoreb);
  k_compact<<<HSIZE/256, 256, 0, stream>>>(hkeys, slot2u, ukeys, Sc);
  k_rank<<<ROWCAP/256, 256, 0, stream>>>(ukeys, rowofu, skeys, Sc);
  k_pass2<<<NPTS/256, 256, 0, stream>>>(slotp, scoreb, maxbits, slot2u, rowofu, rowb, ebuf, denom);
  k_scatter<<<NPTS/64, 256, 0, stream>>>(features, rowb, ebuf, denom, outp);

  dim3 gg(C/128, ROWCAP/128);
  // h1 = vfeat @ w1 + b1
  k_gemm<<<gg, 256, 0, stream>>>(outp, C, C, nullptr, 0, w1, b1, hbufA, C, Sc);
  // LN1 + GELU (in place)
  k_ln_gelu<<<2048, 256, 0, stream>>>(hbufA, hbufA, g1, be1, Sc);
  // h2 = h1 @ w2 + b2
  k_gemm<<<gg, 256, 0, stream>>>(hbufA, C, C, nullptr, 0, w2, b2, hbufB, C, Sc);
  // positional encoding
  k_pos<<<ROWCAP/8, 256, 0, stream>>>(skeys, wp1, bp1, wp2, bp2, pebuf, Sc);
  // tok = concat(h2, pe) @ wf + bf
  k_gemm<<<gg, 256, 0, stream>>>(hbufB, C, C, pebuf, P, wf, bf, hbufA, C+P, Sc);
  // LN2 + GELU -> output (rows >= S stay zero)
  k_ln_gelu<<<2048, 256, 0, stream>>>(hbufA, outp, g2, be2, Sc);
}